// Round 7
// baseline (69.170 us; speedup 1.0000x reference)
//
#include <hip/hip_runtime.h>

// out[b,i,j,c] = sum_d tanh(start[b,c,i,d] + end[b,c,j,d]) * v[d]
// B=2, C=8, L=256, D=128.
//
// tanh(x) = 1 - 2/(e^{2x}+1);  e^{2(s+e)} = Es*Ee, Es=exp2(K*s), K=2*log2(e).
// Per d-quad all 4 divisions merge into ONE rcp (13 full-rate + 1 trans / 4 elem).
// out = sum(v) - 2 * sum_d v_d/q_d,  q_d = fma(Es,Ee,1).
//
// R6 lesson (corrected model): LDS pipe is PER-CU; kernel time fits
// VALU-pipe + LDS-pipe SUM. R4/R6 at 4 B/elem = 10.3 us of LDS alone.
// Fix both: bf16 tiles (range ok: Es <= 2^15.6; RNE error ~0.2% rel) and
// 4x4 per-thread blocking with d split over 4 waves -> 1 B/elem (~2.6 us).
// Unpack = shift/and (exact). 1024 blocks, 4 waves, 16 waves/CU.

#define LDIM 256
#define DDIM 128
#define DPADH 136   // ushort row stride: 272 B = 17x16B, rows 16B-aligned

__device__ __forceinline__ unsigned bf1(float x) {       // f32 -> bf16 (RNE)
    unsigned u = __float_as_uint(x);
    u += 0x7FFFu + ((u >> 16) & 1u);
    return u >> 16;
}
__device__ __forceinline__ unsigned pack2(float x, float y) {
    return bf1(x) | (bf1(y) << 16);
}
__device__ __forceinline__ float lo16(unsigned u) { return __uint_as_float(u << 16); }
__device__ __forceinline__ float hi16(unsigned u) { return __uint_as_float(u & 0xFFFF0000u); }

__global__ __launch_bounds__(256, 4) void span_tanh_dot_kernel(
    const float* __restrict__ start_h,
    const float* __restrict__ end_h,
    const float* __restrict__ v,
    float* __restrict__ out,
    int C)
{
    __shared__ unsigned short s_t[32][DPADH];   // 8.5 KB  (Es, bf16)
    __shared__ unsigned short e_t[32][DPADH];   // 8.5 KB  (Ee, bf16)
    __shared__ float4 red[2 * 64 * 4];          // 8 KB reduction scratch

    const int bc = blockIdx.z;            // b*C + c
    const int i0 = blockIdx.y * 32;
    const int j0 = blockIdx.x * 32;
    const int tx = threadIdx.x;           // 0..7
    const int ty = threadIdx.y;           // 0..7
    const int g  = threadIdx.z;           // 0..3: wave = d-quarter
    const int t  = ty * 8 + tx;
    const int tid = g * 64 + t;

    const float K = 2.8853900817779268f;  // 2*log2(e)

    const float* sg = start_h + ((size_t)bc * LDIM + i0) * DDIM;
    const float* eg = end_h   + ((size_t)bc * LDIM + j0) * DDIM;

    // stage 32x128 tiles as bf16(exp2(K*x)); 512 8-elem chunks/tensor, 2/thread.
    #pragma unroll
    for (int k = 0; k < 2; ++k) {
        const int idx = tid + k * 256;
        const int r  = idx >> 4;
        const int c8 = (idx & 15) << 3;
        float4 a0 = *(const float4*)(sg + r * DDIM + c8);
        float4 a1 = *(const float4*)(sg + r * DDIM + c8 + 4);
        uint4 pa;
        pa.x = pack2(__builtin_amdgcn_exp2f(K * a0.x), __builtin_amdgcn_exp2f(K * a0.y));
        pa.y = pack2(__builtin_amdgcn_exp2f(K * a0.z), __builtin_amdgcn_exp2f(K * a0.w));
        pa.z = pack2(__builtin_amdgcn_exp2f(K * a1.x), __builtin_amdgcn_exp2f(K * a1.y));
        pa.w = pack2(__builtin_amdgcn_exp2f(K * a1.z), __builtin_amdgcn_exp2f(K * a1.w));
        *(uint4*)(&s_t[r][c8]) = pa;
        float4 b0 = *(const float4*)(eg + r * DDIM + c8);
        float4 b1 = *(const float4*)(eg + r * DDIM + c8 + 4);
        uint4 pb;
        pb.x = pack2(__builtin_amdgcn_exp2f(K * b0.x), __builtin_amdgcn_exp2f(K * b0.y));
        pb.y = pack2(__builtin_amdgcn_exp2f(K * b0.z), __builtin_amdgcn_exp2f(K * b0.w));
        pb.z = pack2(__builtin_amdgcn_exp2f(K * b1.x), __builtin_amdgcn_exp2f(K * b1.y));
        pb.w = pack2(__builtin_amdgcn_exp2f(K * b1.z), __builtin_amdgcn_exp2f(K * b1.w));
        *(uint4*)(&e_t[r][c8]) = pb;
    }

    // sum(v) in wave 0 registers (only wave 0 stores at the end)
    float Sv = 0.0f;
    if (g == 0) {
        float2 vv = *(const float2*)(v + 2 * t);
        Sv = vv.x + vv.y;
        #pragma unroll
        for (int off = 1; off < 64; off <<= 1) Sv += __shfl_xor(Sv, off);
    }
    __syncthreads();

    const int gb = __builtin_amdgcn_readfirstlane(g);
    const int dbase = gb * 32;            // wave-uniform d range [dbase, dbase+32)

    float acc[4][4];
    #pragma unroll
    for (int a = 0; a < 4; ++a)
        #pragma unroll
        for (int b = 0; b < 4; ++b) acc[a][b] = 0.0f;

    #pragma unroll
    for (int it = 0; it < 8; ++it) {
        const int d = dbase + it * 4;
        uint2 Sr[4], Er[4];
        #pragma unroll
        for (int k = 0; k < 4; ++k) {
            Sr[k] = *(const uint2*)(&s_t[ty + 8 * k][d]);  // 8 rows x 2 banks: free
            Er[k] = *(const uint2*)(&e_t[tx + 8 * k][d]);
        }
        float Sf[4][4], Ef[4][4];
        #pragma unroll
        for (int k = 0; k < 4; ++k) {
            Sf[k][0] = lo16(Sr[k].x); Sf[k][1] = hi16(Sr[k].x);
            Sf[k][2] = lo16(Sr[k].y); Sf[k][3] = hi16(Sr[k].y);
            Ef[k][0] = lo16(Er[k].x); Ef[k][1] = hi16(Er[k].x);
            Ef[k][2] = lo16(Er[k].y); Ef[k][3] = hi16(Er[k].y);
        }
        const float v0 = v[d], v1 = v[d + 1], v2 = v[d + 2], v3 = v[d + 3];

        #pragma unroll
        for (int a = 0; a < 4; ++a) {
            #pragma unroll
            for (int b = 0; b < 4; ++b) {
                float q0 = fmaf(Sf[a][0], Ef[b][0], 1.0f);
                float q1 = fmaf(Sf[a][1], Ef[b][1], 1.0f);
                float q2 = fmaf(Sf[a][2], Ef[b][2], 1.0f);
                float q3 = fmaf(Sf[a][3], Ef[b][3], 1.0f);
                float ab = q0 * q1, cd = q2 * q3;
                float n01 = fmaf(v0, q1, v1 * q0);
                float n23 = fmaf(v2, q3, v3 * q2);
                float N = fmaf(n01, cd, n23 * ab);
                float r = __builtin_amdgcn_rcpf(ab * cd);
                acc[a][b] = fmaf(N, r, acc[a][b]);
            }
        }
    }

    // combine 4 d-partials: tree over waves {0+2, 1+3}, then {0+1}
    if (g >= 2) {
        #pragma unroll
        for (int a = 0; a < 4; ++a)
            red[((g - 2) * 64 + t) * 4 + a] =
                make_float4(acc[a][0], acc[a][1], acc[a][2], acc[a][3]);
    }
    __syncthreads();
    if (g < 2) {
        #pragma unroll
        for (int a = 0; a < 4; ++a) {
            float4 p = red[(g * 64 + t) * 4 + a];
            acc[a][0] += p.x; acc[a][1] += p.y; acc[a][2] += p.z; acc[a][3] += p.w;
        }
    }
    __syncthreads();
    if (g == 1) {
        #pragma unroll
        for (int a = 0; a < 4; ++a)
            red[t * 4 + a] = make_float4(acc[a][0], acc[a][1], acc[a][2], acc[a][3]);
    }
    __syncthreads();
    if (g == 0) {
        const int b_ = bc / C;
        const int c_ = bc - b_ * C;
        #pragma unroll
        for (int a = 0; a < 4; ++a) {
            float4 p = red[t * 4 + a];
            acc[a][0] += p.x; acc[a][1] += p.y; acc[a][2] += p.z; acc[a][3] += p.w;
            const int i = i0 + ty + 8 * a;
            const size_t rowbase = (((size_t)b_ * LDIM + i) * LDIM) * C + c_;
            #pragma unroll
            for (int b2 = 0; b2 < 4; ++b2) {
                const int j = j0 + tx + 8 * b2;
                out[rowbase + (size_t)j * C] = fmaf(-2.0f, acc[a][b2], Sv);
            }
        }
    }
}

extern "C" void kernel_launch(void* const* d_in, const int* in_sizes, int n_in,
                              void* d_out, int out_size, void* d_ws, size_t ws_size,
                              hipStream_t stream) {
    const float* start_h = (const float*)d_in[0];
    const float* end_h   = (const float*)d_in[1];
    const float* v       = (const float*)d_in[2];
    float* out = (float*)d_out;

    const int BC = in_sizes[0] / (LDIM * DDIM);  // B*C = 16
    const int C  = 8;

    dim3 grid(LDIM / 32, LDIM / 32, BC);   // (8, 8, 16) = 1024 blocks
    dim3 block(8, 8, 4);                   // 256 threads; wave g = d-quarter
    span_tanh_dot_kernel<<<grid, block, 0, stream>>>(start_h, end_h, v, out, C);
}

// Round 8
// 27.415 us; speedup vs baseline: 2.5231x; 2.5231x over previous
//
#include <hip/hip_runtime.h>

// out[b,i,j,c] = sum_d tanh(start[b,c,i,d] + end[b,c,j,d]) * v[d]
// B=2, C=8, L=256, D=128.
//
// tanh(x) = 1 - 2/(e^{2x}+1);  e^{2(s+e)} = Es*Ee, Es=exp2(K*s), K=2*log2(e).
// Per d-quad all 4 divisions merge into ONE rcp (13 full-rate + 1 trans / 4 elem).
// out = sum(v) - 2 * sum_d v_d/q_d,  q_d = fma(Es,Ee,1).
//
// R7 lesson: __launch_bounds__(256,4) capped VGPR at 64 -> Sf/Ef unpack arrays
// spilled to scratch -> 268 MB of HBM spill traffic (the counters showed it:
// VGPR=64, FETCH 132 MB + WRITE 136 MB, VALUBusy 15%). Same structure, no cap:
// bf16 tiles (1 B/elem LDS), 4x4 blocking, d split over 4 waves, and a
// parallel epilogue (all 4 waves combine+store one row-group each).

#define LDIM 256
#define DDIM 128
#define DPADH 136   // ushort row stride: 272 B; rows ty+8k hit banks 4*ty (distinct)

__device__ __forceinline__ unsigned bf1(float x) {       // f32 -> bf16 (RNE)
    unsigned u = __float_as_uint(x);
    u += 0x7FFFu + ((u >> 16) & 1u);
    return u >> 16;
}
__device__ __forceinline__ unsigned pack2(float x, float y) {
    return bf1(x) | (bf1(y) << 16);
}
__device__ __forceinline__ float lo16(unsigned u) { return __uint_as_float(u << 16); }
__device__ __forceinline__ float hi16(unsigned u) { return __uint_as_float(u & 0xFFFF0000u); }

__global__ __launch_bounds__(256) void span_tanh_dot_kernel(
    const float* __restrict__ start_h,
    const float* __restrict__ end_h,
    const float* __restrict__ v,
    float* __restrict__ out,
    int C)
{
    __shared__ unsigned short s_t[32][DPADH];   // 8.5 KB  (Es, bf16)
    __shared__ unsigned short e_t[32][DPADH];   // 8.5 KB  (Ee, bf16)
    __shared__ float4 red[4 * 64 * 4];          // 16 KB: all-wave partials

    const int bc = blockIdx.z;            // b*C + c
    const int i0 = blockIdx.y * 32;
    const int j0 = blockIdx.x * 32;
    const int tx = threadIdx.x;           // 0..7
    const int ty = threadIdx.y;           // 0..7
    const int g  = threadIdx.z;           // 0..3: wave = d-quarter
    const int t  = ty * 8 + tx;
    const int tid = g * 64 + t;

    const float K = 2.8853900817779268f;  // 2*log2(e)

    const float* sg = start_h + ((size_t)bc * LDIM + i0) * DDIM;
    const float* eg = end_h   + ((size_t)bc * LDIM + j0) * DDIM;

    // stage 32x128 tiles as bf16(exp2(K*x)); 512 8-elem chunks/tensor, 2/thread.
    #pragma unroll
    for (int k = 0; k < 2; ++k) {
        const int idx = tid + k * 256;
        const int r  = idx >> 4;
        const int c8 = (idx & 15) << 3;
        float4 a0 = *(const float4*)(sg + r * DDIM + c8);
        float4 a1 = *(const float4*)(sg + r * DDIM + c8 + 4);
        uint4 pa;
        pa.x = pack2(__builtin_amdgcn_exp2f(K * a0.x), __builtin_amdgcn_exp2f(K * a0.y));
        pa.y = pack2(__builtin_amdgcn_exp2f(K * a0.z), __builtin_amdgcn_exp2f(K * a0.w));
        pa.z = pack2(__builtin_amdgcn_exp2f(K * a1.x), __builtin_amdgcn_exp2f(K * a1.y));
        pa.w = pack2(__builtin_amdgcn_exp2f(K * a1.z), __builtin_amdgcn_exp2f(K * a1.w));
        *(uint4*)(&s_t[r][c8]) = pa;
        float4 b0 = *(const float4*)(eg + r * DDIM + c8);
        float4 b1 = *(const float4*)(eg + r * DDIM + c8 + 4);
        uint4 pb;
        pb.x = pack2(__builtin_amdgcn_exp2f(K * b0.x), __builtin_amdgcn_exp2f(K * b0.y));
        pb.y = pack2(__builtin_amdgcn_exp2f(K * b0.z), __builtin_amdgcn_exp2f(K * b0.w));
        pb.z = pack2(__builtin_amdgcn_exp2f(K * b1.x), __builtin_amdgcn_exp2f(K * b1.y));
        pb.w = pack2(__builtin_amdgcn_exp2f(K * b1.z), __builtin_amdgcn_exp2f(K * b1.w));
        *(uint4*)(&e_t[r][c8]) = pb;
    }

    // sum(v): every wave butterfly-reduces (all waves store output later)
    float Sv;
    {
        float2 vv = *(const float2*)(v + 2 * t);
        Sv = vv.x + vv.y;
        #pragma unroll
        for (int off = 1; off < 64; off <<= 1) Sv += __shfl_xor(Sv, off);
    }
    __syncthreads();

    const int gb = __builtin_amdgcn_readfirstlane(g);
    const int dbase = gb * 32;            // wave-uniform -> v loads become s_load

    float acc[4][4];
    #pragma unroll
    for (int a = 0; a < 4; ++a)
        #pragma unroll
        for (int b = 0; b < 4; ++b) acc[a][b] = 0.0f;

    #pragma unroll
    for (int it = 0; it < 8; ++it) {
        const int d = dbase + it * 4;
        uint2 Sr[4], Er[4];
        #pragma unroll
        for (int k = 0; k < 4; ++k) {
            Sr[k] = *(const uint2*)(&s_t[ty + 8 * k][d]);  // banks 4*ty: conflict-free
            Er[k] = *(const uint2*)(&e_t[tx + 8 * k][d]);
        }
        float Sf[4][4], Ef[4][4];
        #pragma unroll
        for (int k = 0; k < 4; ++k) {
            Sf[k][0] = lo16(Sr[k].x); Sf[k][1] = hi16(Sr[k].x);
            Sf[k][2] = lo16(Sr[k].y); Sf[k][3] = hi16(Sr[k].y);
            Ef[k][0] = lo16(Er[k].x); Ef[k][1] = hi16(Er[k].x);
            Ef[k][2] = lo16(Er[k].y); Ef[k][3] = hi16(Er[k].y);
        }
        const float v0 = v[d], v1 = v[d + 1], v2 = v[d + 2], v3 = v[d + 3];

        #pragma unroll
        for (int a = 0; a < 4; ++a) {
            #pragma unroll
            for (int b = 0; b < 4; ++b) {
                float q0 = fmaf(Sf[a][0], Ef[b][0], 1.0f);
                float q1 = fmaf(Sf[a][1], Ef[b][1], 1.0f);
                float q2 = fmaf(Sf[a][2], Ef[b][2], 1.0f);
                float q3 = fmaf(Sf[a][3], Ef[b][3], 1.0f);
                float ab = q0 * q1, cd = q2 * q3;
                float n01 = fmaf(v0, q1, v1 * q0);
                float n23 = fmaf(v2, q3, v3 * q2);
                float N = fmaf(n01, cd, n23 * ab);
                float r = __builtin_amdgcn_rcpf(ab * cd);
                acc[a][b] = fmaf(N, r, acc[a][b]);
            }
        }
    }

    // park all partials (slot-skewed), one barrier, each wave combines+stores
    // row-group a = g. Stores spread over all 256 threads.
    #pragma unroll
    for (int a = 0; a < 4; ++a)
        red[(g * 64 + t) * 4 + ((a + t) & 3)] =
            make_float4(acc[a][0], acc[a][1], acc[a][2], acc[a][3]);
    __syncthreads();

    float4 sum = red[t * 4 + ((g + t) & 3)];
    #pragma unroll
    for (int src = 1; src < 4; ++src) {
        const float4 p = red[(src * 64 + t) * 4 + ((g + t) & 3)];
        sum.x += p.x; sum.y += p.y; sum.z += p.z; sum.w += p.w;
    }

    const int b_ = bc / C;
    const int c_ = bc - b_ * C;
    const int i = i0 + ty + 8 * g;
    const int j = j0 + tx;
    const size_t rowbase = (((size_t)b_ * LDIM + i) * LDIM) * C + c_;
    out[rowbase + (size_t)(j     ) * C] = fmaf(-2.f, sum.x, Sv);
    out[rowbase + (size_t)(j +  8) * C] = fmaf(-2.f, sum.y, Sv);
    out[rowbase + (size_t)(j + 16) * C] = fmaf(-2.f, sum.z, Sv);
    out[rowbase + (size_t)(j + 24) * C] = fmaf(-2.f, sum.w, Sv);
}

extern "C" void kernel_launch(void* const* d_in, const int* in_sizes, int n_in,
                              void* d_out, int out_size, void* d_ws, size_t ws_size,
                              hipStream_t stream) {
    const float* start_h = (const float*)d_in[0];
    const float* end_h   = (const float*)d_in[1];
    const float* v       = (const float*)d_in[2];
    float* out = (float*)d_out;

    const int BC = in_sizes[0] / (LDIM * DDIM);  // B*C = 16
    const int C  = 8;

    dim3 grid(LDIM / 32, LDIM / 32, BC);   // (8, 8, 16) = 1024 blocks
    dim3 block(8, 8, 4);                   // 256 threads; wave g = d-quarter
    span_tanh_dot_kernel<<<grid, block, 0, stream>>>(start_h, end_h, v, out, C);
}

// Round 9
// 19.042 us; speedup vs baseline: 3.6326x; 1.4397x over previous
//
#include <hip/hip_runtime.h>

// out[b,i,j,c] = sum_d tanh(start[b,c,i,d] + end[b,c,j,d]) * v[d]
// B=2, C=8, L=256, D=128.
//
// tanh(x) = 1 - 2/(e^{2x}+1);  e^{2(s+e)} = Es*Ee, Es=exp2(K*s), K=2*log2(e).
// Per d-quad all 4 divisions merge into ONE rcp (13 full-rate + 1 trans / 4 el).
// out = sum(v) - 2 * sum_d v_d/q_d,  q_d = fma(Es,Ee,1).
//
// Model (fits R2-R8): time ~ VALU-pipe + LDS-pipe (poor overlap) + overhead.
// R5 proved the 4x4 d-split inner loop (2 B/elem LDS), but its float4
// reduction epilogue had a 16-word lane stride -> ~16-way bank conflicts
// (~4-5 us). This round: same inner loop, scalar b32 epilogue at lane
// stride 1 (2 words/bank = free), aliased into dead s_t. Named scalars
// everywhere (R7/R8: arrays -> scratch risk).

#define LDIM 256
#define DDIM 128
#define DPAD 132   // 132 mod 32 = 4 -> rows ty+8k start at bank 4*ty: conflict-free

__global__ __launch_bounds__(256) void span_tanh_dot_kernel(
    const float* __restrict__ start_h,
    const float* __restrict__ end_h,
    const float* __restrict__ v,
    float* __restrict__ out,
    int C)
{
    __shared__ float s_pool[32 * DPAD];      // Es tile; later reduction buffer
    __shared__ float e_t[32][DPAD];          // Ee tile
    __shared__ float s_vsum;
    float (*s_t)[DPAD] = (float (*)[DPAD])s_pool;

    const int bc = blockIdx.z;               // b*C + c
    const int i0 = blockIdx.y * 32;
    const int j0 = blockIdx.x * 32;
    const int tx = threadIdx.x;              // 0..7
    const int ty = threadIdx.y;              // 0..7
    const int g  = threadIdx.z;              // 0..3: wave = d-quarter
    const int t  = ty * 8 + tx;              // lane in wave
    const int tid = g * 64 + t;

    const float K = 2.8853900817779268f;     // 2*log2(e)

    const float* sg = start_h + ((size_t)bc * LDIM + i0) * DDIM;
    const float* eg = end_h   + ((size_t)bc * LDIM + j0) * DDIM;

    // stage 32x128 tiles of Es=exp2(K*s), Ee=exp2(K*e); 4 float4/thread/tensor
    #pragma unroll
    for (int k = 0; k < 4; ++k) {
        const int idx = tid + k * 256;
        const int r  = idx >> 5;
        const int c4 = (idx & 31) << 2;
        float4 a = *(const float4*)(sg + r * DDIM + c4);
        a.x = __builtin_amdgcn_exp2f(K * a.x);
        a.y = __builtin_amdgcn_exp2f(K * a.y);
        a.z = __builtin_amdgcn_exp2f(K * a.z);
        a.w = __builtin_amdgcn_exp2f(K * a.w);
        *(float4*)(&s_t[r][c4]) = a;
        float4 b = *(const float4*)(eg + r * DDIM + c4);
        b.x = __builtin_amdgcn_exp2f(K * b.x);
        b.y = __builtin_amdgcn_exp2f(K * b.y);
        b.z = __builtin_amdgcn_exp2f(K * b.z);
        b.w = __builtin_amdgcn_exp2f(K * b.w);
        *(float4*)(&e_t[r][c4]) = b;
    }

    // sum(v): wave 0 butterfly -> LDS broadcast
    if (g == 0) {
        float2 vv = *(const float2*)(v + 2 * t);
        float p = vv.x + vv.y;
        #pragma unroll
        for (int off = 1; off < 64; off <<= 1) p += __shfl_xor(p, off);
        if (t == 0) s_vsum = p;
    }
    __syncthreads();

    const int dbase = __builtin_amdgcn_readfirstlane(g) * 32;  // wave-uniform

    float acc00 = 0.f, acc01 = 0.f, acc02 = 0.f, acc03 = 0.f;
    float acc10 = 0.f, acc11 = 0.f, acc12 = 0.f, acc13 = 0.f;
    float acc20 = 0.f, acc21 = 0.f, acc22 = 0.f, acc23 = 0.f;
    float acc30 = 0.f, acc31 = 0.f, acc32 = 0.f, acc33 = 0.f;

#define QUAD(ACC, S, E)                                            \
    {                                                              \
        float q0 = fmaf((S).x, (E).x, 1.0f);                       \
        float q1 = fmaf((S).y, (E).y, 1.0f);                       \
        float q2 = fmaf((S).z, (E).z, 1.0f);                       \
        float q3 = fmaf((S).w, (E).w, 1.0f);                       \
        float ab = q0 * q1, cd = q2 * q3;                          \
        float n01 = fmaf(v0, q1, v1 * q0);                         \
        float n23 = fmaf(v2, q3, v3 * q2);                         \
        float N = fmaf(n01, cd, n23 * ab);                         \
        float r = __builtin_amdgcn_rcpf(ab * cd);                  \
        ACC = fmaf(N, r, ACC);                                     \
    }

    #pragma unroll 2
    for (int it = 0; it < 8; ++it) {
        const int d = dbase + it * 4;
        const float4 s0 = *(const float4*)(&s_t[ty     ][d]);  // banks 4ty: free
        const float4 s1 = *(const float4*)(&s_t[ty +  8][d]);
        const float4 s2 = *(const float4*)(&s_t[ty + 16][d]);
        const float4 s3 = *(const float4*)(&s_t[ty + 24][d]);
        const float4 e0 = *(const float4*)(&e_t[tx     ][d]);
        const float4 e1 = *(const float4*)(&e_t[tx +  8][d]);
        const float4 e2 = *(const float4*)(&e_t[tx + 16][d]);
        const float4 e3 = *(const float4*)(&e_t[tx + 24][d]);
        const float v0 = v[d], v1 = v[d + 1], v2 = v[d + 2], v3 = v[d + 3];

        QUAD(acc00, s0, e0); QUAD(acc01, s0, e1); QUAD(acc02, s0, e2); QUAD(acc03, s0, e3);
        QUAD(acc10, s1, e0); QUAD(acc11, s1, e1); QUAD(acc12, s1, e2); QUAD(acc13, s1, e3);
        QUAD(acc20, s2, e0); QUAD(acc21, s2, e1); QUAD(acc22, s2, e2); QUAD(acc23, s2, e3);
        QUAD(acc30, s3, e0); QUAD(acc31, s3, e1); QUAD(acc32, s3, e2); QUAD(acc33, s3, e3);
    }
#undef QUAD

    // ---- conflict-free cross-wave d-reduction, aliased into s_t ----
    // slot(a,b,src,t) = ((a*4+b)*4 + src)*64 + t : lane stride 1 word (free)
    __syncthreads();                        // everyone done reading s_t
    float* red = s_pool;
#define PARK(A, B, ACC) red[(((A) * 4 + (B)) * 4 + g) * 64 + t] = ACC;
    PARK(0,0,acc00) PARK(0,1,acc01) PARK(0,2,acc02) PARK(0,3,acc03)
    PARK(1,0,acc10) PARK(1,1,acc11) PARK(1,2,acc12) PARK(1,3,acc13)
    PARK(2,0,acc20) PARK(2,1,acc21) PARK(2,2,acc22) PARK(2,3,acc23)
    PARK(3,0,acc30) PARK(3,1,acc31) PARK(3,2,acc32) PARK(3,3,acc33)
#undef PARK
    __syncthreads();

    // wave g combines row-group a = g (4 b32 reads per output, stride-1 lanes)
#define COMB(B)                                                    \
    (red[((g * 4 + (B)) * 4 + 0) * 64 + t] +                       \
     red[((g * 4 + (B)) * 4 + 1) * 64 + t] +                       \
     red[((g * 4 + (B)) * 4 + 2) * 64 + t] +                       \
     red[((g * 4 + (B)) * 4 + 3) * 64 + t])
    const float o0 = COMB(0);
    const float o1 = COMB(1);
    const float o2 = COMB(2);
    const float o3 = COMB(3);
#undef COMB

    const int b_ = bc / C;
    const int c_ = bc - b_ * C;
    const float Sv = s_vsum;
    const int i = i0 + ty + 8 * g;
    const size_t rowbase = (((size_t)b_ * LDIM + i) * LDIM) * C + c_;
    out[rowbase + (size_t)(j0 + tx     ) * C] = fmaf(-2.f, o0, Sv);
    out[rowbase + (size_t)(j0 + tx +  8) * C] = fmaf(-2.f, o1, Sv);
    out[rowbase + (size_t)(j0 + tx + 16) * C] = fmaf(-2.f, o2, Sv);
    out[rowbase + (size_t)(j0 + tx + 24) * C] = fmaf(-2.f, o3, Sv);
}

extern "C" void kernel_launch(void* const* d_in, const int* in_sizes, int n_in,
                              void* d_out, int out_size, void* d_ws, size_t ws_size,
                              hipStream_t stream) {
    const float* start_h = (const float*)d_in[0];
    const float* end_h   = (const float*)d_in[1];
    const float* v       = (const float*)d_in[2];
    float* out = (float*)d_out;

    const int BC = in_sizes[0] / (LDIM * DDIM);  // B*C = 16
    const int C  = 8;

    dim3 grid(LDIM / 32, LDIM / 32, BC);   // (8, 8, 16) = 1024 blocks, 4/CU
    dim3 block(8, 8, 4);                   // 256 threads; wave g = d-quarter
    span_tanh_dot_kernel<<<grid, block, 0, stream>>>(start_h, end_h, v, out, C);
}

// Round 10
// 18.387 us; speedup vs baseline: 3.7618x; 1.0356x over previous
//
#include <hip/hip_runtime.h>

// out[b,i,j,c] = sum_d tanh(start[b,c,i,d] + end[b,c,j,d]) * v[d]
// B=2, C=8, L=256, D=128.
//
// tanh(x) = 1 - 2/(e^{2x}+1);  e^{2(s+e)} = Es*Ee, Es=exp2(K*s), K=2*log2(e).
// u-substitution (R10): w_d = 1/v_d, stage Es' = Es*w_d, then
//   u_d = fma(Es',Ee,w_d) = q_d*w_d  and  sum_d v_d/q_d = sum_d 1/u_d
//   = [cd*(u0+u1) + ab*(u2+u3)] / (ab*cd)
// -> numerator pairs are ADDs, not fma+mul: 11 full-rate + 1 rcp per 4 elems
// (was 14+1).  out = sum(v) - 2 * sum_d 1/u_d.
// |u| >= 10 always (q>1, |w|>=10); worst-case D ~ 3e22 << f32max; the
// u0+u1 cancellation error divides back out (~1e-11 on output).
//
// Structure = R9 (best so far): 32x32 tile, d split over 4 waves, 4x4
// per-thread blocking (2 B/elem LDS), conflict-free strided reads,
// lane-stride-1 epilogue. w quads come from pad cols 128..131 of s_t via
// one same-address broadcast ds_read_b128 per iter.

#define LDIM 256
#define DDIM 128
#define DPAD 132   // 132 mod 32 = 4 -> rows ty+8k start at bank 4*ty: conflict-free

__global__ __launch_bounds__(256) void span_tanh_dot_kernel(
    const float* __restrict__ start_h,
    const float* __restrict__ end_h,
    const float* __restrict__ v,
    float* __restrict__ out,
    int C)
{
    __shared__ float s_pool[32 * DPAD];      // Es' tile (+w pad); later reduction buf
    __shared__ float e_t[32][DPAD];          // Ee tile
    __shared__ float s_vsum;
    float (*s_t)[DPAD] = (float (*)[DPAD])s_pool;

    const int bc = blockIdx.z;               // b*C + c
    const int i0 = blockIdx.y * 32;
    const int j0 = blockIdx.x * 32;
    const int tx = threadIdx.x;              // 0..7
    const int ty = threadIdx.y;              // 0..7
    const int g  = threadIdx.z;              // 0..3: wave = d-quarter
    const int t  = ty * 8 + tx;              // lane in wave
    const int tid = g * 64 + t;

    const float K = 2.8853900817779268f;     // 2*log2(e)

    const float* sg = start_h + ((size_t)bc * LDIM + i0) * DDIM;
    const float* eg = end_h   + ((size_t)bc * LDIM + j0) * DDIM;

    // stage 32x128 tiles: s_t = exp2(K*s)/v_d ; e_t = exp2(K*e)
    #pragma unroll
    for (int k = 0; k < 4; ++k) {
        const int idx = tid + k * 256;
        const int r  = idx >> 5;
        const int c4 = (idx & 31) << 2;
        const float4 vv = *(const float4*)(v + c4);
        const float w0 = __builtin_amdgcn_rcpf(vv.x);
        const float w1 = __builtin_amdgcn_rcpf(vv.y);
        const float w2 = __builtin_amdgcn_rcpf(vv.z);
        const float w3 = __builtin_amdgcn_rcpf(vv.w);
        float4 a = *(const float4*)(sg + r * DDIM + c4);
        a.x = __builtin_amdgcn_exp2f(K * a.x) * w0;
        a.y = __builtin_amdgcn_exp2f(K * a.y) * w1;
        a.z = __builtin_amdgcn_exp2f(K * a.z) * w2;
        a.w = __builtin_amdgcn_exp2f(K * a.w) * w3;
        *(float4*)(&s_t[r][c4]) = a;
        float4 b = *(const float4*)(eg + r * DDIM + c4);
        b.x = __builtin_amdgcn_exp2f(K * b.x);
        b.y = __builtin_amdgcn_exp2f(K * b.y);
        b.z = __builtin_amdgcn_exp2f(K * b.z);
        b.w = __builtin_amdgcn_exp2f(K * b.w);
        *(float4*)(&e_t[r][c4]) = b;
    }

    // w table into the unused pad cols of s_t: w[d] at s_t[d>>2][128+(d&3)]
    if (tid < 128) {
        s_t[tid >> 2][128 + (tid & 3)] = __builtin_amdgcn_rcpf(v[tid]);
    }

    // sum(v): wave 0 butterfly -> LDS broadcast
    if (g == 0) {
        float2 vv = *(const float2*)(v + 2 * t);
        float p = vv.x + vv.y;
        #pragma unroll
        for (int off = 1; off < 64; off <<= 1) p += __shfl_xor(p, off);
        if (t == 0) s_vsum = p;
    }
    __syncthreads();

    const int g8 = __builtin_amdgcn_readfirstlane(g) * 8;  // wave-uniform row base

    float acc00 = 0.f, acc01 = 0.f, acc02 = 0.f, acc03 = 0.f;
    float acc10 = 0.f, acc11 = 0.f, acc12 = 0.f, acc13 = 0.f;
    float acc20 = 0.f, acc21 = 0.f, acc22 = 0.f, acc23 = 0.f;
    float acc30 = 0.f, acc31 = 0.f, acc32 = 0.f, acc33 = 0.f;

#define QUAD(ACC, S, E)                                            \
    {                                                              \
        float u0 = fmaf((S).x, (E).x, W.x);                        \
        float u1 = fmaf((S).y, (E).y, W.y);                        \
        float u2 = fmaf((S).z, (E).z, W.z);                        \
        float u3 = fmaf((S).w, (E).w, W.w);                        \
        float ab = u0 * u1, cd = u2 * u3;                          \
        float n01 = u0 + u1;                                       \
        float n23 = u2 + u3;                                       \
        float N = fmaf(n01, cd, n23 * ab);                         \
        float r = __builtin_amdgcn_rcpf(ab * cd);                  \
        ACC = fmaf(N, r, ACC);                                     \
    }

    #pragma unroll 2
    for (int it = 0; it < 8; ++it) {
        const int d = (g8 + it) * 4;
        const float4 W  = *(const float4*)(&s_t[g8 + it][128]);   // broadcast: free
        const float4 s0 = *(const float4*)(&s_t[ty     ][d]);     // banks 4ty: free
        const float4 s1 = *(const float4*)(&s_t[ty +  8][d]);
        const float4 s2 = *(const float4*)(&s_t[ty + 16][d]);
        const float4 s3 = *(const float4*)(&s_t[ty + 24][d]);
        const float4 e0 = *(const float4*)(&e_t[tx     ][d]);
        const float4 e1 = *(const float4*)(&e_t[tx +  8][d]);
        const float4 e2 = *(const float4*)(&e_t[tx + 16][d]);
        const float4 e3 = *(const float4*)(&e_t[tx + 24][d]);

        QUAD(acc00, s0, e0); QUAD(acc01, s0, e1); QUAD(acc02, s0, e2); QUAD(acc03, s0, e3);
        QUAD(acc10, s1, e0); QUAD(acc11, s1, e1); QUAD(acc12, s1, e2); QUAD(acc13, s1, e3);
        QUAD(acc20, s2, e0); QUAD(acc21, s2, e1); QUAD(acc22, s2, e2); QUAD(acc23, s2, e3);
        QUAD(acc30, s3, e0); QUAD(acc31, s3, e1); QUAD(acc32, s3, e2); QUAD(acc33, s3, e3);
    }
#undef QUAD

    // ---- conflict-free cross-wave d-reduction, aliased into s_t ----
    // slot(a,b,src,t) = ((a*4+b)*4 + src)*64 + t : lane stride 1 word (free)
    __syncthreads();                        // everyone done reading s_t
    float* red = s_pool;
#define PARK(A, B, ACC) red[(((A) * 4 + (B)) * 4 + g) * 64 + t] = ACC;
    PARK(0,0,acc00) PARK(0,1,acc01) PARK(0,2,acc02) PARK(0,3,acc03)
    PARK(1,0,acc10) PARK(1,1,acc11) PARK(1,2,acc12) PARK(1,3,acc13)
    PARK(2,0,acc20) PARK(2,1,acc21) PARK(2,2,acc22) PARK(2,3,acc23)
    PARK(3,0,acc30) PARK(3,1,acc31) PARK(3,2,acc32) PARK(3,3,acc33)
#undef PARK
    __syncthreads();

    // wave g combines row-group a = g (4 b32 reads per output, stride-1 lanes)
#define COMB(B)                                                    \
    (red[((g * 4 + (B)) * 4 + 0) * 64 + t] +                       \
     red[((g * 4 + (B)) * 4 + 1) * 64 + t] +                       \
     red[((g * 4 + (B)) * 4 + 2) * 64 + t] +                       \
     red[((g * 4 + (B)) * 4 + 3) * 64 + t])
    const float o0 = COMB(0);
    const float o1 = COMB(1);
    const float o2 = COMB(2);
    const float o3 = COMB(3);
#undef COMB

    const int b_ = bc / C;
    const int c_ = bc - b_ * C;
    const float Sv = s_vsum;
    const int i = i0 + ty + 8 * g;
    const size_t rowbase = (((size_t)b_ * LDIM + i) * LDIM) * C + c_;
    out[rowbase + (size_t)(j0 + tx     ) * C] = fmaf(-2.f, o0, Sv);
    out[rowbase + (size_t)(j0 + tx +  8) * C] = fmaf(-2.f, o1, Sv);
    out[rowbase + (size_t)(j0 + tx + 16) * C] = fmaf(-2.f, o2, Sv);
    out[rowbase + (size_t)(j0 + tx + 24) * C] = fmaf(-2.f, o3, Sv);
}

extern "C" void kernel_launch(void* const* d_in, const int* in_sizes, int n_in,
                              void* d_out, int out_size, void* d_ws, size_t ws_size,
                              hipStream_t stream) {
    const float* start_h = (const float*)d_in[0];
    const float* end_h   = (const float*)d_in[1];
    const float* v       = (const float*)d_in[2];
    float* out = (float*)d_out;

    const int BC = in_sizes[0] / (LDIM * DDIM);  // B*C = 16
    const int C  = 8;

    dim3 grid(LDIM / 32, LDIM / 32, BC);   // (8, 8, 16) = 1024 blocks, 4/CU
    dim3 block(8, 8, 4);                   // 256 threads; wave g = d-quarter
    span_tanh_dot_kernel<<<grid, block, 0, stream>>>(start_h, end_h, v, out, C);
}